// Round 4
// baseline (333.577 us; speedup 1.0000x reference)
//
#include <hip/hip_runtime.h>
#include <math.h>

#define CLASSNUM 70722
#define BATCH 512
#define EMBD 512
#define M_C 0.4f
#define H_C 0.333f
#define S_C 64.0f
#define EPS_C 0.001f
#define PI_F 3.14159265358979f

typedef __bf16 bf16_t;
typedef __bf16 bf16x8 __attribute__((ext_vector_type(8)));
typedef float f32x4 __attribute__((ext_vector_type(4)));

__device__ __forceinline__ float clampf(float x, float lo, float hi) {
    return fminf(fmaxf(x, lo), hi);
}

// ---------------------------------------------------------------------------
// prep_lab (unchanged, verified): blocks 0..127 convert emb fp32->bf16 into
// MFMA-fragment order; blocks 128..639 compute the exact fp32 label-column
// values (margin formula) into labout.
// ---------------------------------------------------------------------------
__global__ __launch_bounds__(256) void prep_lab_kernel(
    const float* __restrict__ emb, const float* __restrict__ norms,
    const float* __restrict__ csn, const int* __restrict__ label,
    const float* __restrict__ kmat, bf16_t* __restrict__ Aws,
    float* __restrict__ labout)
{
    __shared__ float red[256];
    const int tid = threadIdx.x;
    const int bi = blockIdx.x;

    if (bi < 128) {
        const int G = bi * 256 + tid;           // granule id, 0..32767
        const int kt = G >> 11;                 // k-slab (32 k per slab)
        const int rem = G & 2047;
        const int rg = rem >> 6;                // 16-row group, 0..31
        const int lane = rem & 63;
        const int row = rg * 16 + (lane & 15);
        const int k0 = kt * 32 + (lane >> 4) * 8;
        const float* src = emb + row * EMBD + k0;
        const float4 v0 = *(const float4*)src;
        const float4 v1 = *(const float4*)(src + 4);
        bf16x8 bw;
        bw[0] = (bf16_t)v0.x; bw[1] = (bf16_t)v0.y;
        bw[2] = (bf16_t)v0.z; bw[3] = (bf16_t)v0.w;
        bw[4] = (bf16_t)v1.x; bw[5] = (bf16_t)v1.y;
        bw[6] = (bf16_t)v1.z; bw[7] = (bf16_t)v1.w;
        *(bf16x8*)(Aws + (size_t)G * 8) = bw;   // coalesced 16 B store
        return;
    }

    const int b = bi - 128;

    float s0, s1;
    {
        float sn = clampf(norms[tid], 0.001f, 100.0f);
        sn = sn / (csn[tid] + 0.001f);
        s0 = clampf(sn, 0.001f, 100.0f);
    }
    {
        float sn = clampf(norms[tid + 256], 0.001f, 100.0f);
        sn = sn / (csn[tid + 256] + 0.001f);
        s1 = clampf(sn, 0.001f, 100.0f);
    }
    red[tid] = s0 + s1;
    __syncthreads();
    for (int off = 128; off > 0; off >>= 1) {
        if (tid < off) red[tid] += red[tid + off];
        __syncthreads();
    }
    const float mean = red[0] * (1.0f / 512.0f);
    __syncthreads();
    const float d0 = s0 - mean, d1 = s1 - mean;
    red[tid] = d0 * d0 + d1 * d1;
    __syncthreads();
    for (int off = 128; off > 0; off >>= 1) {
        if (tid < off) red[tid] += red[tid + off];
        __syncthreads();
    }
    const float stdv = sqrtf(red[0] * (1.0f / 511.0f));   // ddof=1
    __syncthreads();

    const int lab = label[b];
    const float* col = kmat + lab;
    const float* e = emb + b * EMBD;
    float dot = 0.0f, ss = 0.0f;
#pragma unroll
    for (int k = tid; k < EMBD; k += 256) {
        const float kv = col[(size_t)k * CLASSNUM];
        const float ev = e[k];
        dot = fmaf(ev, kv, dot);
        ss  = fmaf(kv, kv, ss);
    }
    red[tid] = dot;
    __syncthreads();
    for (int off = 128; off > 0; off >>= 1) {
        if (tid < off) red[tid] += red[tid + off];
        __syncthreads();
    }
    const float dotT = red[0];
    __syncthreads();
    red[tid] = ss;
    __syncthreads();
    for (int off = 128; off > 0; off >>= 1) {
        if (tid < off) red[tid] += red[tid + off];
        __syncthreads();
    }
    if (tid == 0) {
        const float ssT = red[0];
        float c = dotT / sqrtf(ssT);
        c = clampf(c, -1.0f + EPS_C, 1.0f - EPS_C);
        float snb = clampf(norms[b], 0.001f, 100.0f);
        snb = snb / (csn[b] + 0.001f);
        snb = clampf(snb, 0.001f, 100.0f);
        const float msv = clampf((snb - mean) / (stdv + EPS_C) * H_C, -1.0f, 1.0f);
        float th = acosf(c) - M_C * msv;
        th = clampf(th, EPS_C, PI_F - EPS_C);
        labout[b] = (cosf(th) - (M_C + M_C * msv)) * S_C;
    }
}

// ---------------------------------------------------------------------------
// gemm v4: MT=256 x NT=64 per block, 256 threads = 4 waves (wave-tile 64x64).
// Per-wave registers identical to v3 (64 acc + ~64) -> 4 waves/SIMD ->
// 4 blocks/CU = 16 waves/CU in FOUR independent barrier domains (v3 had two
// 8-wave domains); one domain's A/B latency stall is filled by the other
// three.  K is logically read twice (2 M-halves) but K (145 MB) fits in the
// 256 MB L3 and both halves of a column window run on the same XCD (swizzle),
// so the second read is L2/L3-hit, not HBM.  B staged cooperatively (8
// strided dwords/thread/sub-iter, 2 sub-iters ahead), counted vmcnt across
// raw s_barrier (never drained).  Scatter + column-norm epilogue fused.
// ---------------------------------------------------------------------------

#define LOADB8(t, dst) do {                                             \
    const size_t ko_ = (size_t)((t) * 32) * CLASSNUM;                   \
    _Pragma("unroll")                                                   \
    for (int j_ = 0; j_ < 8; ++j_)                                      \
        dst[j_] = bp[ko_ + (size_t)j_ * CLASSNUM];                      \
} while (0)

#define LOADA4(t, af) do {                                              \
    const bf16x8* ap_ = (const bf16x8*)Aws                              \
        + (((t) * 32 + mbase + wave * 4) * 64 + lane);                  \
    _Pragma("unroll")                                                   \
    for (int mi_ = 0; mi_ < 4; ++mi_) af[mi_] = ap_[mi_ * 64];          \
} while (0)

#define CVTW8(src, buf) do {                                            \
    bf16x8 w_;                                                          \
    _Pragma("unroll")                                                   \
    for (int j_ = 0; j_ < 8; ++j_) {                                    \
        const float v_ = src[j_];                                       \
        ssq = fmaf(v_, v_, ssq);                                        \
        w_[j_] = (bf16_t)v_;                                            \
    }                                                                   \
    *(bf16x8*)&Blds[buf][c * 40 + kg * 8] = w_;                         \
} while (0)

#define MFMA16(af, buf) do {                                            \
    bf16x8 bfr_[4];                                                     \
    _Pragma("unroll")                                                   \
    for (int ni_ = 0; ni_ < 4; ++ni_)                                   \
        bfr_[ni_] = *(const bf16x8*)                                    \
            &Blds[buf][(ni_ * 16 + r16) * 40 + quad * 8];               \
    __builtin_amdgcn_s_setprio(1);                                      \
    _Pragma("unroll")                                                   \
    for (int mi_ = 0; mi_ < 4; ++mi_)                                   \
        _Pragma("unroll")                                               \
        for (int ni_ = 0; ni_ < 4; ++ni_)                               \
            acc[mi_][ni_] = __builtin_amdgcn_mfma_f32_16x16x32_bf16(    \
                af[mi_], bfr_[ni_], acc[mi_][ni_], 0, 0, 0);            \
    __builtin_amdgcn_s_setprio(0);                                      \
} while (0)

#define BARRIER() do {                                                  \
    asm volatile("s_waitcnt lgkmcnt(0)" ::: "memory");                  \
    __builtin_amdgcn_s_barrier();                                       \
} while (0)

__global__ __launch_bounds__(256, 4) void gemm_kernel(
    const bf16_t* __restrict__ Aws, const float* __restrict__ Kmat,
    const int* __restrict__ label, const float* __restrict__ labout,
    float* __restrict__ out)
{
    __shared__ bf16_t Blds[2][64 * 40];     // padded stride 40: 2-way read/write
    __shared__ float red[256];
    __shared__ float invn_s[64];
    __shared__ int   lab_s[256];
    __shared__ float lo_s[256];

    const int tid  = threadIdx.x;
    const int lane = tid & 63;
    const int wave = tid >> 6;              // 0..3
    const int r16  = lane & 15;
    const int quad = lane >> 4;

    // bijective XCD swizzle over nwg = 2212 (= 8*276 + 4); consecutive swz
    // ids land on one XCD, and (col-window, mhalf) pairs are swz-adjacent ->
    // both M-halves of a column window share that XCD's L2/L3 for B.
    const int nwg = 2 * ((CLASSNUM + 63) / 64);          // 2212
    const int q_ = nwg >> 3, r_ = nwg & 7;               // 276, 4
    const int xcd = blockIdx.x & 7, idx = blockIdx.x >> 3;
    const int swz = (xcd < r_) ? (xcd * (q_ + 1) + idx)
                               : (r_ * (q_ + 1) + (xcd - r_) * q_ + idx);
    const int mhalf = swz & 1;               // 0 / 1 -> rows 0..255 / 256..511
    const int n0    = (swz >> 1) * 64;
    const int mbase = mhalf * 16;            // fragment row-group base

    lab_s[tid] = label[mhalf * 256 + tid];
    lo_s[tid]  = labout[mhalf * 256 + tid];

    // B cooperative-load ownership: col c (0..63), k-group kg (0..3) of 8 k.
    const int c  = tid & 63;
    const int kg = tid >> 6;
    int cg = n0 + c;
    if (cg >= CLASSNUM) cg = CLASSNUM - 1;   // clamp; stores are guarded
    const float* bp = Kmat + (size_t)(kg * 8) * CLASSNUM + cg;

    f32x4 acc[4][4];
    const f32x4 zero = {0.0f, 0.0f, 0.0f, 0.0f};
#pragma unroll
    for (int i = 0; i < 4; ++i)
#pragma unroll
        for (int j = 0; j < 4; ++j) acc[i][j] = zero;
    float ssq = 0.0f;

    float bv0[8], bv1[8];

    // ---- prologue: B(0)->bv0, B(1)->bv1, stage B(0) into Blds[0] ----
    LOADB8(0, bv0);
    LOADB8(1, bv1);
    CVTW8(bv0, 0);
    BARRIER();

    // ---- K loop, hand-unrolled x2 (static buffer names).  Per sub-iter:
    // LOADA first, then LOADB(it+2) -> the MFMA dep-wait is vmcnt(8),
    // leaving the B(it+2) loads in flight across the barrier. ----
#pragma unroll 1
    for (int p = 0; p < 8; ++p) {
        {   // it = 2p (even): MFMA on Blds[0]; stage B(2p+1) -> Blds[1]
            bf16x8 af[4];
            LOADA4(2 * p, af);
            if (p < 7) LOADB8(2 * p + 2, bv0);
            MFMA16(af, 0);
            CVTW8(bv1, 1);
            BARRIER();
        }
        {   // it = 2p+1 (odd): MFMA on Blds[1]; stage B(2p+2) -> Blds[0]
            bf16x8 af[4];
            LOADA4(2 * p + 1, af);
            if (p < 7) LOADB8(2 * p + 3, bv1);
            MFMA16(af, 1);
            if (p < 7) CVTW8(bv0, 0);
            BARRIER();
        }
    }

    // ---- column inverse norms: 4 k-partials per column (kg groups) ----
    red[tid] = ssq;
    __syncthreads();
    if (tid < 64) {
        const float s = red[tid] + red[tid + 64] + red[tid + 128] + red[tid + 192];
        invn_s[tid] = (s > 0.0f) ? (1.0f / sqrtf(s)) : 0.0f;
    }
    __syncthreads();

    // ---- epilogue: out = S * clip(cosine); label entries substituted ----
#pragma unroll
    for (int mi = 0; mi < 4; ++mi) {
#pragma unroll
        for (int rr = 0; rr < 4; ++rr) {
            const int rowl = wave * 64 + mi * 16 + quad * 4 + rr;   // 0..255
            const int labc = lab_s[rowl];
            const float lov = lo_s[rowl];
            float* orow = out + (size_t)(mhalf * 256 + rowl) * CLASSNUM;
#pragma unroll
            for (int ni = 0; ni < 4; ++ni) {
                const int col_loc = ni * 16 + r16;
                const int col = n0 + col_loc;
                if (col < CLASSNUM) {
                    const float cc = clampf(acc[mi][ni][rr] * invn_s[col_loc],
                                            -1.0f + EPS_C, 1.0f - EPS_C);
                    float v = cc * S_C;
                    if (labc == col) v = lov;
                    orow[col] = v;
                }
            }
        }
    }
}

extern "C" void kernel_launch(void* const* d_in, const int* in_sizes, int n_in,
                              void* d_out, int out_size, void* d_ws, size_t ws_size,
                              hipStream_t stream)
{
    const float* emb   = (const float*)d_in[0];
    const float* norms = (const float*)d_in[1];
    const int*   label = (const int*)d_in[2];
    const float* csn   = (const float*)d_in[3];
    const float* kmat  = (const float*)d_in[4];
    float* out = (float*)d_out;

    // workspace: [A bf16 fragment-tiled 512x512 | labout 512]
    const size_t A_BYTES = (size_t)BATCH * EMBD * sizeof(bf16_t);  // 524288
    if (ws_size < A_BYTES + 4096) return;
    bf16_t* Aws   = (bf16_t*)d_ws;
    float* labout = (float*)((char*)d_ws + A_BYTES);

    prep_lab_kernel<<<128 + BATCH, 256, 0, stream>>>(
        emb, norms, csn, label, kmat, Aws, labout);
    const int nblk = 2 * ((CLASSNUM + 63) / 64);   // 2212
    gemm_kernel<<<nblk, 256, 0, stream>>>(Aws, kmat, label, labout, out);
}

// Round 5
// 331.656 us; speedup vs baseline: 1.0058x; 1.0058x over previous
//
#include <hip/hip_runtime.h>
#include <math.h>

#define CLASSNUM 70722
#define BATCH 512
#define EMBD 512
#define M_C 0.4f
#define H_C 0.333f
#define S_C 64.0f
#define EPS_C 0.001f
#define PI_F 3.14159265358979f

typedef __bf16 bf16_t;
typedef __bf16 bf16x8 __attribute__((ext_vector_type(8)));
typedef float f32x4 __attribute__((ext_vector_type(4)));

__device__ __forceinline__ float clampf(float x, float lo, float hi) {
    return fminf(fmaxf(x, lo), hi);
}

// ---------------------------------------------------------------------------
// prep_lab (unchanged, verified): blocks 0..127 convert emb fp32->bf16 into
// MFMA-fragment order; blocks 128..639 compute the exact fp32 label-column
// values (margin formula) into labout.
// ---------------------------------------------------------------------------
__global__ __launch_bounds__(256) void prep_lab_kernel(
    const float* __restrict__ emb, const float* __restrict__ norms,
    const float* __restrict__ csn, const int* __restrict__ label,
    const float* __restrict__ kmat, bf16_t* __restrict__ Aws,
    float* __restrict__ labout)
{
    __shared__ float red[256];
    const int tid = threadIdx.x;
    const int bi = blockIdx.x;

    if (bi < 128) {
        const int G = bi * 256 + tid;           // granule id, 0..32767
        const int kt = G >> 11;                 // k-slab (32 k per slab)
        const int rem = G & 2047;
        const int rg = rem >> 6;                // 16-row group, 0..31
        const int lane = rem & 63;
        const int row = rg * 16 + (lane & 15);
        const int k0 = kt * 32 + (lane >> 4) * 8;
        const float* src = emb + row * EMBD + k0;
        const float4 v0 = *(const float4*)src;
        const float4 v1 = *(const float4*)(src + 4);
        bf16x8 bw;
        bw[0] = (bf16_t)v0.x; bw[1] = (bf16_t)v0.y;
        bw[2] = (bf16_t)v0.z; bw[3] = (bf16_t)v0.w;
        bw[4] = (bf16_t)v1.x; bw[5] = (bf16_t)v1.y;
        bw[6] = (bf16_t)v1.z; bw[7] = (bf16_t)v1.w;
        *(bf16x8*)(Aws + (size_t)G * 8) = bw;   // coalesced 16 B store
        return;
    }

    const int b = bi - 128;

    float s0, s1;
    {
        float sn = clampf(norms[tid], 0.001f, 100.0f);
        sn = sn / (csn[tid] + 0.001f);
        s0 = clampf(sn, 0.001f, 100.0f);
    }
    {
        float sn = clampf(norms[tid + 256], 0.001f, 100.0f);
        sn = sn / (csn[tid + 256] + 0.001f);
        s1 = clampf(sn, 0.001f, 100.0f);
    }
    red[tid] = s0 + s1;
    __syncthreads();
    for (int off = 128; off > 0; off >>= 1) {
        if (tid < off) red[tid] += red[tid + off];
        __syncthreads();
    }
    const float mean = red[0] * (1.0f / 512.0f);
    __syncthreads();
    const float d0 = s0 - mean, d1 = s1 - mean;
    red[tid] = d0 * d0 + d1 * d1;
    __syncthreads();
    for (int off = 128; off > 0; off >>= 1) {
        if (tid < off) red[tid] += red[tid + off];
        __syncthreads();
    }
    const float stdv = sqrtf(red[0] * (1.0f / 511.0f));   // ddof=1
    __syncthreads();

    const int lab = label[b];
    const float* col = kmat + lab;
    const float* e = emb + b * EMBD;
    float dot = 0.0f, ss = 0.0f;
#pragma unroll
    for (int k = tid; k < EMBD; k += 256) {
        const float kv = col[(size_t)k * CLASSNUM];
        const float ev = e[k];
        dot = fmaf(ev, kv, dot);
        ss  = fmaf(kv, kv, ss);
    }
    red[tid] = dot;
    __syncthreads();
    for (int off = 128; off > 0; off >>= 1) {
        if (tid < off) red[tid] += red[tid + off];
        __syncthreads();
    }
    const float dotT = red[0];
    __syncthreads();
    red[tid] = ss;
    __syncthreads();
    for (int off = 128; off > 0; off >>= 1) {
        if (tid < off) red[tid] += red[tid + off];
        __syncthreads();
    }
    if (tid == 0) {
        const float ssT = red[0];
        float c = dotT / sqrtf(ssT);
        c = clampf(c, -1.0f + EPS_C, 1.0f - EPS_C);
        float snb = clampf(norms[b], 0.001f, 100.0f);
        snb = snb / (csn[b] + 0.001f);
        snb = clampf(snb, 0.001f, 100.0f);
        const float msv = clampf((snb - mean) / (stdv + EPS_C) * H_C, -1.0f, 1.0f);
        float th = acosf(c) - M_C * msv;
        th = clampf(th, EPS_C, PI_F - EPS_C);
        labout[b] = (cosf(th) - (M_C + M_C * msv)) * S_C;
    }
}

// ---------------------------------------------------------------------------
// gemm v5: v4 geometry (MT=256 x NT=64, 256 thr = 4 waves, wave-tile 64x64,
// 2212 blocks pair-swizzled per XCD) with a DEPTH-ALIGNED pipeline.
//
// Key fact: vmcnt drains in ISSUE ORDER -- a wait on a younger load forces
// every older outstanding load complete.  So each load must be issued with
// >= its latency of lead before ANY wait point can force it:
//   - B (HBM, ~900 cy): triple-buffered regs bv[3][8], issued 3 steps
//     (~1050 cy) before its convert.
//   - A (L2, ~200-300 cy): double-buffered af[2][4], issued at the START of
//     the previous step -- A(p) is then OLDER than B(p+2..) in the queue, so
//     the MFMA's A-wait only forces B(p+1), which already has 3 steps of age.
// K-loop fully unrolled (16 steps) so all buffer indices are static.
// Raw s_barrier + lgkmcnt(0) only; vm loads keep crossing barriers.
// ---------------------------------------------------------------------------

#define LOADB8(t, dst) do {                                             \
    const size_t ko_ = (size_t)((t) * 32) * CLASSNUM;                   \
    _Pragma("unroll")                                                   \
    for (int j_ = 0; j_ < 8; ++j_)                                      \
        dst[j_] = bp[ko_ + (size_t)j_ * CLASSNUM];                      \
} while (0)

#define LOADA4(t, af) do {                                              \
    const bf16x8* ap_ = (const bf16x8*)Aws                              \
        + (((t) * 32 + mbase + wave * 4) * 64 + lane);                  \
    _Pragma("unroll")                                                   \
    for (int mi_ = 0; mi_ < 4; ++mi_) af[mi_] = ap_[mi_ * 64];          \
} while (0)

#define CVTW8(src, buf) do {                                            \
    bf16x8 w_;                                                          \
    _Pragma("unroll")                                                   \
    for (int j_ = 0; j_ < 8; ++j_) {                                    \
        const float v_ = src[j_];                                       \
        ssq = fmaf(v_, v_, ssq);                                        \
        w_[j_] = (bf16_t)v_;                                            \
    }                                                                   \
    *(bf16x8*)&Blds[buf][c * 40 + kg * 8] = w_;                         \
} while (0)

#define MFMA16(af, buf) do {                                            \
    bf16x8 bfr_[4];                                                     \
    _Pragma("unroll")                                                   \
    for (int ni_ = 0; ni_ < 4; ++ni_)                                   \
        bfr_[ni_] = *(const bf16x8*)                                    \
            &Blds[buf][(ni_ * 16 + r16) * 40 + quad * 8];               \
    __builtin_amdgcn_s_setprio(1);                                      \
    _Pragma("unroll")                                                   \
    for (int mi_ = 0; mi_ < 4; ++mi_)                                   \
        _Pragma("unroll")                                               \
        for (int ni_ = 0; ni_ < 4; ++ni_)                               \
            acc[mi_][ni_] = __builtin_amdgcn_mfma_f32_16x16x32_bf16(    \
                af[mi_], bfr_[ni_], acc[mi_][ni_], 0, 0, 0);            \
    __builtin_amdgcn_s_setprio(0);                                      \
} while (0)

#define BARRIER() do {                                                  \
    asm volatile("s_waitcnt lgkmcnt(0)" ::: "memory");                  \
    __builtin_amdgcn_s_barrier();                                       \
} while (0)

__global__ __launch_bounds__(256, 3) void gemm_kernel(
    const bf16_t* __restrict__ Aws, const float* __restrict__ Kmat,
    const int* __restrict__ label, const float* __restrict__ labout,
    float* __restrict__ out)
{
    __shared__ bf16_t Blds[2][64 * 40];     // padded stride 40
    __shared__ float red[256];
    __shared__ float invn_s[64];
    __shared__ int   lab_s[256];
    __shared__ float lo_s[256];

    const int tid  = threadIdx.x;
    const int lane = tid & 63;
    const int wave = tid >> 6;              // 0..3
    const int r16  = lane & 15;
    const int quad = lane >> 4;

    // bijective XCD swizzle over nwg = 2212 (= 8*276 + 4); (col-window,
    // mhalf) pairs are swz-adjacent -> both M-halves of a column window
    // share one XCD's L2/L3 for B.
    const int nwg = 2 * ((CLASSNUM + 63) / 64);          // 2212
    const int q_ = nwg >> 3, r_ = nwg & 7;               // 276, 4
    const int xcd = blockIdx.x & 7, idx = blockIdx.x >> 3;
    const int swz = (xcd < r_) ? (xcd * (q_ + 1) + idx)
                               : (r_ * (q_ + 1) + (xcd - r_) * q_ + idx);
    const int mhalf = swz & 1;               // 0 / 1 -> rows 0..255 / 256..511
    const int n0    = (swz >> 1) * 64;
    const int mbase = mhalf * 16;            // fragment row-group base

    lab_s[tid] = label[mhalf * 256 + tid];
    lo_s[tid]  = labout[mhalf * 256 + tid];

    // B cooperative-load ownership: col c (0..63), k-group kg (0..3) of 8 k.
    const int c  = tid & 63;
    const int kg = tid >> 6;
    int cg = n0 + c;
    if (cg >= CLASSNUM) cg = CLASSNUM - 1;   // clamp; stores are guarded
    const float* bp = Kmat + (size_t)(kg * 8) * CLASSNUM + cg;

    f32x4 acc[4][4];
    const f32x4 zero = {0.0f, 0.0f, 0.0f, 0.0f};
#pragma unroll
    for (int i = 0; i < 4; ++i)
#pragma unroll
        for (int j = 0; j < 4; ++j) acc[i][j] = zero;
    float ssq = 0.0f;

    float  bv[3][8];        // B(t) lives in bv[t%3]; 3-step issue lead
    bf16x8 af[2][4];        // A(p) lives in af[p%2]; issued at step p-1

    // ---- prologue ----
    LOADB8(0, bv[0]);
    LOADB8(1, bv[1]);
    LOADB8(2, bv[2]);
    LOADA4(0, af[0]);
    CVTW8(bv[0], 0);        // B(0) -> Blds[0]
    LOADB8(3, bv[0]);       // refill freed slot
    BARRIER();

    // ---- K loop: 16 steps, fully unrolled (all indices static) ----
    // step p: [A(p+1) issue] [MFMA on Blds[p&1] with af[p&1]]
    //         [CVT B(p+1)->Blds[(p+1)&1]] [B(p+4) issue] [barrier]
#pragma unroll
    for (int p = 0; p < 16; ++p) {
        if (p < 15) LOADA4(p + 1, af[(p + 1) & 1]);
        MFMA16(af[p & 1], p & 1);
        if (p < 15) CVTW8(bv[(p + 1) % 3], (p + 1) & 1);
        if (p < 12) LOADB8(p + 4, bv[(p + 1) % 3]);
        if (p < 15) BARRIER();
    }

    // ---- column inverse norms: 4 k-partials per column (kg groups) ----
    red[tid] = ssq;
    __syncthreads();
    if (tid < 64) {
        const float s = red[tid] + red[tid + 64] + red[tid + 128] + red[tid + 192];
        invn_s[tid] = (s > 0.0f) ? (1.0f / sqrtf(s)) : 0.0f;
    }
    __syncthreads();

    // ---- epilogue: out = S * clip(cosine); label entries substituted ----
#pragma unroll
    for (int mi = 0; mi < 4; ++mi) {
#pragma unroll
        for (int rr = 0; rr < 4; ++rr) {
            const int rowl = wave * 64 + mi * 16 + quad * 4 + rr;   // 0..255
            const int labc = lab_s[rowl];
            const float lov = lo_s[rowl];
            float* orow = out + (size_t)(mhalf * 256 + rowl) * CLASSNUM;
#pragma unroll
            for (int ni = 0; ni < 4; ++ni) {
                const int col_loc = ni * 16 + r16;
                const int col = n0 + col_loc;
                if (col < CLASSNUM) {
                    const float cc = clampf(acc[mi][ni][rr] * invn_s[col_loc],
                                            -1.0f + EPS_C, 1.0f - EPS_C);
                    float v = cc * S_C;
                    if (labc == col) v = lov;
                    orow[col] = v;
                }
            }
        }
    }
}

extern "C" void kernel_launch(void* const* d_in, const int* in_sizes, int n_in,
                              void* d_out, int out_size, void* d_ws, size_t ws_size,
                              hipStream_t stream)
{
    const float* emb   = (const float*)d_in[0];
    const float* norms = (const float*)d_in[1];
    const int*   label = (const int*)d_in[2];
    const float* csn   = (const float*)d_in[3];
    const float* kmat  = (const float*)d_in[4];
    float* out = (float*)d_out;

    // workspace: [A bf16 fragment-tiled 512x512 | labout 512]
    const size_t A_BYTES = (size_t)BATCH * EMBD * sizeof(bf16_t);  // 524288
    if (ws_size < A_BYTES + 4096) return;
    bf16_t* Aws   = (bf16_t*)d_ws;
    float* labout = (float*)((char*)d_ws + A_BYTES);

    prep_lab_kernel<<<128 + BATCH, 256, 0, stream>>>(
        emb, norms, csn, label, kmat, Aws, labout);
    const int nblk = 2 * ((CLASSNUM + 63) / 64);   // 2212
    gemm_kernel<<<nblk, 256, 0, stream>>>(Aws, kmat, label, labout, out);
}